// Round 9
// baseline (271.096 us; speedup 1.0000x reference)
//
#include <hip/hip_runtime.h>
#include <math.h>

#define B_ 2
#define L_ 2048
#define H_ 16
#define E_ 64
#define D_ 64
#define DM_ 512
#define DH_ 256
#define GRID_ 512

typedef __bf16 bf16_t;
typedef bf16_t bf16x8_t __attribute__((ext_vector_type(8)));
typedef float f32x4_t __attribute__((ext_vector_type(4)));

// pack two floats to bf16x2 (round-up-at-halfway; 2 add + 1 perm)
__device__ __forceinline__ unsigned bpack(float hi, float lo) {
    unsigned uh = __float_as_uint(hi) + 0x8000u;
    unsigned ul = __float_as_uint(lo) + 0x8000u;
    return __builtin_amdgcn_perm(uh, ul, 0x07060302u);
}

__device__ __forceinline__ bf16_t to_bf16(float f) {
    union { float f; unsigned u; } x; x.f = f;
    unsigned r = (x.u + 0x7fffu + ((x.u >> 16) & 1u)) >> 16;
    union { unsigned short s; bf16_t b; } y; y.s = (unsigned short)r;
    return y.b;
}

struct TileRegs { f32x4_t k[4]; float v[16]; float m; };

// ---- single fused kernel: MLP -> grid barrier -> flash attention ----------
// 512 blocks x 256 thr, 37.4KB LDS, <=128 VGPR (launch_bounds 256,4) -> 4
// blocks/CU capacity = 1024 >= 512: all blocks co-resident by construction,
// so the counter barrier cannot deadlock. Counter zeroed per replay by
// hipMemsetAsync on the stream (graph-capture legal).
__global__ __launch_bounds__(256, 4) void fused_kernel(
        const float* __restrict__ Q, const float* __restrict__ K,
        const float* __restrict__ V, const float* __restrict__ raw,
        const float* __restrict__ w1, const float* __restrict__ b1,
        const float* __restrict__ w2, const float* __restrict__ alpha_trend,
        float* __restrict__ fused4, int* __restrict__ bar,
        float* __restrict__ out) {
    __shared__ union {
        struct { bf16_t Ks[2][64][72]; bf16_t Vt[2][64][72]; float moms[2][64]; } a;
        struct { bf16_t Rs[16][520]; float part[4][16]; } m;
    } S;

    const int tid = threadIdx.x;
    const int bid = blockIdx.x;
    const int wave = tid >> 6, lane = tid & 63;
    const int lrow = lane & 15, lgrp = lane >> 4;

    // ================= phase A: MLP (one m-tile, two n-quarters) ===========
    {
        const int m0 = (bid >> 1) * 16;
        const int nq0 = (bid & 1) << 1;        // quarters {0,1} or {2,3}
        #pragma unroll
        for (int u = 0; u < 8; ++u) {
            int idx = tid + u * 256;
            int row = idx >> 7;
            int k = (idx & 127) << 2;
            f32x4_t v = *(const f32x4_t*)&raw[(size_t)(m0 + row) * DM_ + k];
            uint2 p;
            p.x = bpack(v[1], v[0]);
            p.y = bpack(v[3], v[2]);
            *(uint2*)&S.m.Rs[row][k] = p;
        }
        __syncthreads();
        #pragma unroll
        for (int qq = 0; qq < 2; ++qq) {
            const int nq = nq0 + qq;
            const int n = nq * 64 + wave * 16 + lrow;
            f32x4_t acc = (f32x4_t){0.f, 0.f, 0.f, 0.f};
            const float* wcol = w1 + n;        // w1[k][n], stride DH_
            #pragma unroll
            for (int s = 0; s < 16; ++s) {
                bf16x8_t a = *(const bf16x8_t*)&S.m.Rs[lrow][s * 32 + lgrp * 8];
                const float* wp = wcol + (size_t)(s * 32 + lgrp * 8) * DH_;
                bf16x8_t bfr;
                #pragma unroll
                for (int j = 0; j < 8; ++j) bfr[j] = to_bf16(wp[(size_t)j * DH_]);
                acc = __builtin_amdgcn_mfma_f32_16x16x32_bf16(a, bfr, acc, 0, 0, 0);
            }
            const float b1v = b1[n];
            const float w2v = w2[n];
            float rowpart[4];
            #pragma unroll
            for (int r = 0; r < 4; ++r) {
                float hh = acc[r] + b1v;
                hh = hh > 0.f ? hh : 0.f;
                rowpart[r] = hh * w2v;
            }
            #pragma unroll
            for (int r = 0; r < 4; ++r) {
                float v = rowpart[r];
                v += __shfl_xor(v, 1);
                v += __shfl_xor(v, 2);
                v += __shfl_xor(v, 4);
                v += __shfl_xor(v, 8);
                if (lrow == 0) S.m.part[wave][lgrp * 4 + r] = v;
            }
            __syncthreads();
            if (tid < 16)
                fused4[nq * (B_ * L_) + m0 + tid] =
                    S.m.part[0][tid] + S.m.part[1][tid] + S.m.part[2][tid] + S.m.part[3][tid];
            __syncthreads();
        }
    }

    // ================= grid barrier (all 512 blocks co-resident) ===========
    __threadfence();
    __syncthreads();
    if (tid == 0) {
        __hip_atomic_fetch_add(bar, 1, __ATOMIC_ACQ_REL, __HIP_MEMORY_SCOPE_AGENT);
        while (__hip_atomic_load(bar, __ATOMIC_ACQUIRE, __HIP_MEMORY_SCOPE_AGENT) < GRID_)
            __builtin_amdgcn_s_sleep(2);
    }
    __syncthreads();
    __threadfence();

    // ================= phase B: attention, two q-tiles per block ===========
    const int bh = bid & 31;
    const int grp = bid >> 5;              // 0..15
    const int h = bh & 15, b = bh >> 4;

    const float c1 = 0.18033688f;          // 0.125 * log2(e)
    const float ascale2 = alpha_trend[h] * c1;
    const size_t bl = (size_t)b * L_;

    const float* Kb = K + (bl * H_ + h) * E_;
    const float* Vb = V + (bl * H_ + h) * D_;
    const float* f4 = fused4 + bl;         // + nq*4096 per partial

    auto fsum = [&](int i) {
        return f4[i] + f4[4096 + i] + f4[8192 + i] + f4[12288 + i];
    };
    auto mom_at = [&](int i) { return (i > 0) ? fsum(i) - fsum(i - 1) : 0.f; };

    // staging thread mapping (R1-proven reg-staged pipeline)
    const int krow = tid >> 4;
    const int ke0  = (tid & 15) << 2;
    const int p0   = (krow & 3) | (((krow >> 3) & 1) << 2) | (((krow >> 2) & 1) << 4);
    const int vd   = tid & 63;
    const int vsb  = tid >> 6;
    const int vswz = ((vd >> 3) & 7) << 4;
    char* const vtbase = (char*)S.a.Vt;

    #pragma unroll 1
    for (int half = 0; half < 2; ++half) {
        const int qt = half ? (31 - grp) : grp;   // qtA+qtB = 31: 33 steps/block
        const int q0 = qt << 6;
        const int qw0 = q0 + wave * 16;
        const int qg = qw0 + lrow;

        // Q fragments, prescaled by c1 (RNE, once)
        bf16x8_t a_lo, a_hi;
        {
            const float* qp = Q + ((bl + qw0 + lrow) * H_ + h) * E_ + lgrp * 8;
            f32x4_t v0 = *(const f32x4_t*)(qp);
            f32x4_t v1 = *(const f32x4_t*)(qp + 4);
            f32x4_t v2 = *(const f32x4_t*)(qp + 32);
            f32x4_t v3 = *(const f32x4_t*)(qp + 36);
            #pragma unroll
            for (int k = 0; k < 4; ++k) {
                a_lo[k]     = to_bf16(v0[k] * c1);
                a_lo[4 + k] = to_bf16(v1[k] * c1);
                a_hi[k]     = to_bf16(v2[k] * c1);
                a_hi[4 + k] = to_bf16(v3[k] * c1);
            }
        }
        const float mq = mom_at(qg);

        f32x4_t Oacc[4];
        #pragma unroll
        for (int c = 0; c < 4; ++c) Oacc[c] = (f32x4_t){0.f, 0.f, 0.f, 0.f};
        float rowsum = 0.f;

        // prologue: preload tile 0 into registers
        TileRegs tr;
        {
            #pragma unroll
            for (int u = 0; u < 4; ++u)
                tr.k[u] = *(const f32x4_t*)&Kb[(krow + u * 16) * (H_ * E_) + ke0];
            #pragma unroll
            for (int j = 0; j < 16; ++j)
                tr.v[j] = Vb[(vsb * 16 + j) * (H_ * D_) + vd];
            tr.m = (tid < 64) ? mom_at(tid) : 0.f;
        }
        __syncthreads();   // previous phase/half done with LDS

        for (int st = 0; st <= qt; ++st) {
            const int buf = st & 1;
            bf16_t (*Ksb)[72] = S.a.Ks[buf];
            char* vtb = vtbase + buf * (64 * 144);

            // registers -> LDS (bf16 packed). K rows go to permuted positions.
            #pragma unroll
            for (int u = 0; u < 4; ++u) {
                uint2 p;
                p.x = bpack(tr.k[u][1], tr.k[u][0]);
                p.y = bpack(tr.k[u][3], tr.k[u][2]);
                int pr = p0 + (u & 1) * 8 + (u >> 1) * 32;
                *(uint2*)&Ksb[pr][ke0] = p;
            }
            #pragma unroll
            for (int u = 0; u < 4; ++u) {
                uint2 p;
                p.x = bpack(tr.v[u * 4 + 1], tr.v[u * 4 + 0]);
                p.y = bpack(tr.v[u * 4 + 3], tr.v[u * 4 + 2]);
                int boff = (vsb * 32 + u * 8) ^ vswz;
                *(uint2*)(vtb + vd * 144 + boff) = p;
            }
            if (tid < 64) S.a.moms[buf][tid] = tr.m;
            __syncthreads();   // single barrier per step (double-buffered LDS)

            // issue next tile's global loads (latency hidden behind compute)
            if (st < qt) {
                const int s0n = (st + 1) << 6;
                #pragma unroll
                for (int u = 0; u < 4; ++u)
                    tr.k[u] = *(const f32x4_t*)&Kb[(s0n + krow + u * 16) * (H_ * E_) + ke0];
                #pragma unroll
                for (int j = 0; j < 16; ++j)
                    tr.v[j] = Vb[(s0n + vsb * 16 + j) * (H_ * D_) + vd];
                tr.m = (tid < 64) ? mom_at(s0n + tid) : 0.f;
            }

            // S^T = K Q^T (swapped operands; log2 domain via Q prescale)
            f32x4_t Sacc[4];
            #pragma unroll
            for (int c = 0; c < 4; ++c) Sacc[c] = (f32x4_t){0.f, 0.f, 0.f, 0.f};
            __builtin_amdgcn_s_setprio(1);
            #pragma unroll
            for (int c = 0; c < 4; ++c) {
                bf16x8_t k_lo = *(const bf16x8_t*)&Ksb[c * 16 + lrow][lgrp * 8];
                bf16x8_t k_hi = *(const bf16x8_t*)&Ksb[c * 16 + lrow][32 + lgrp * 8];
                Sacc[c] = __builtin_amdgcn_mfma_f32_16x16x32_bf16(k_lo, a_lo, Sacc[c], 0, 0, 0);
                Sacc[c] = __builtin_amdgcn_mfma_f32_16x16x32_bf16(k_hi, a_hi, Sacc[c], 0, 0, 0);
            }
            __builtin_amdgcn_s_setprio(0);

            // P = exp2(S - ascale2*|dm|)
            float rowe[4][4];
            #pragma unroll
            for (int c = 0; c < 4; ++c) {
                const int sb = lgrp * 8 + ((c & 1) << 2) + ((c >> 1) << 5);
                f32x4_t ms4 = *(const f32x4_t*)&S.a.moms[buf][sb];
                #pragma unroll
                for (int r = 0; r < 4; ++r) {
                    float arg = Sacc[c][r] - ascale2 * fabsf(mq - ms4[r]);
                    rowe[c][r] = __builtin_amdgcn_exp2f(arg);
                }
            }
            if (st == qt) {                // causal mask on diagonal tile
                const int s0 = st << 6;
                #pragma unroll
                for (int c = 0; c < 4; ++c) {
                    const int sg0 = s0 + lgrp * 8 + ((c & 1) << 2) + ((c >> 1) << 5);
                    #pragma unroll
                    for (int r = 0; r < 4; ++r)
                        if (sg0 + r > qg) rowe[c][r] = 0.f;
                }
            }
            #pragma unroll
            for (int c = 0; c < 4; ++c)
                rowsum += (rowe[c][0] + rowe[c][1]) + (rowe[c][2] + rowe[c][3]);

            // O += P V : P fragments lane-local, pack to bf16
            #pragma unroll
            for (int hh = 0; hh < 2; ++hh) {
                union { unsigned u[4]; bf16x8_t v; } pa;
                pa.u[0] = bpack(rowe[2 * hh][1],     rowe[2 * hh][0]);
                pa.u[1] = bpack(rowe[2 * hh][3],     rowe[2 * hh][2]);
                pa.u[2] = bpack(rowe[2 * hh + 1][1], rowe[2 * hh + 1][0]);
                pa.u[3] = bpack(rowe[2 * hh + 1][3], rowe[2 * hh + 1][2]);
                __builtin_amdgcn_s_setprio(1);
                #pragma unroll
                for (int c2 = 0; c2 < 4; ++c2) {
                    const int row = c2 * 16 + lrow;
                    int boff = (hh * 64 + lgrp * 16) ^ (((row >> 3) & 7) << 4);
                    bf16x8_t bv = *(const bf16x8_t*)(vtb + row * 144 + boff);
                    Oacc[c2] = __builtin_amdgcn_mfma_f32_16x16x32_bf16(pa.v, bv, Oacc[c2], 0, 0, 0);
                }
                __builtin_amdgcn_s_setprio(0);
            }
        }

        // epilogue: full row sums via 2 shuffles, normalize, store
        float rs = rowsum;
        rs += __shfl_xor(rs, 16);
        rs += __shfl_xor(rs, 32);
        #pragma unroll
        for (int r = 0; r < 4; ++r) {
            float inv = 1.f / __shfl(rs, lgrp * 4 + r);
            size_t orow = ((bl + qw0 + lgrp * 4 + r) * H_ + h) * D_;
            #pragma unroll
            for (int c = 0; c < 4; ++c)
                out[orow + c * 16 + lrow] = Oacc[c][r] * inv;
        }
    }
}

extern "C" void kernel_launch(void* const* d_in, const int* in_sizes, int n_in,
                              void* d_out, int out_size, void* d_ws, size_t ws_size,
                              hipStream_t stream) {
    const float* Q     = (const float*)d_in[0];
    const float* K     = (const float*)d_in[1];
    const float* V     = (const float*)d_in[2];
    const float* raw   = (const float*)d_in[3];
    const float* w1    = (const float*)d_in[4];
    const float* b1    = (const float*)d_in[5];
    const float* w2    = (const float*)d_in[6];
    const float* alpha = (const float*)d_in[8];
    float* out = (float*)d_out;

    int*   bar    = (int*)d_ws;                        // barrier counter
    float* fused4 = (float*)((char*)d_ws + 256);       // 4 x 4096 f32 partials

    hipMemsetAsync(bar, 0, 256, stream);               // re-zero each replay
    fused_kernel<<<GRID_, 256, 0, stream>>>(Q, K, V, raw, w1, b1, w2, alpha,
                                            fused4, bar, out);
}

// Round 10
// 167.231 us; speedup vs baseline: 1.6211x; 1.6211x over previous
//
#include <hip/hip_runtime.h>
#include <math.h>

#define B_ 2
#define L_ 2048
#define H_ 16
#define E_ 64
#define D_ 64
#define DM_ 512
#define DH_ 256

typedef __bf16 bf16_t;
typedef bf16_t bf16x8_t __attribute__((ext_vector_type(8)));
typedef float f32x4_t __attribute__((ext_vector_type(4)));

// pack two floats to bf16x2 (round-up-at-halfway; 2 add + 1 perm)
__device__ __forceinline__ unsigned bpack(float hi, float lo) {
    unsigned uh = __float_as_uint(hi) + 0x8000u;
    unsigned ul = __float_as_uint(lo) + 0x8000u;
    return __builtin_amdgcn_perm(uh, ul, 0x07060302u);
}

__device__ __forceinline__ bf16_t to_bf16(float f) {
    union { float f; unsigned u; } x; x.f = f;
    unsigned r = (x.u + 0x7fffu + ((x.u >> 16) & 1u)) >> 16;
    union { unsigned short s; bf16_t b; } y; y.s = (unsigned short)r;
    return y.b;
}

struct TileRegs { f32x4_t k[4]; float v[16]; float m; };

// ---------------- MLP: fused4[nq][m] = sum_n relu(raw@w1+b1)*w2 --------------
// 1024 blocks; block = 16 rows x 64-n quarter; direct strided w1 reads (f32,
// L2-hot); unique-writer partials -> no atomics, no init, no transpose kernel.
// b2 dropped (cancels in the momentum diff).
__global__ __launch_bounds__(256) void mlp_kernel(
        const float* __restrict__ raw, const float* __restrict__ w1,
        const float* __restrict__ b1, const float* __restrict__ w2,
        float* __restrict__ fused4) {
    __shared__ bf16_t Rs[16][520];
    __shared__ float part[4][16];
    const int t = threadIdx.x;
    const int m0 = (blockIdx.x >> 2) * 16;
    const int nq = blockIdx.x & 3;     // n-quarter
    #pragma unroll
    for (int u = 0; u < 8; ++u) {
        int idx = t + u * 256;
        int row = idx >> 7;
        int k = (idx & 127) << 2;
        f32x4_t v = *(const f32x4_t*)&raw[(size_t)(m0 + row) * DM_ + k];
        uint2 p;
        p.x = bpack(v[1], v[0]);
        p.y = bpack(v[3], v[2]);
        *(uint2*)&Rs[row][k] = p;
    }
    __syncthreads();
    const int wave = t >> 6;
    const int lane = t & 63;
    const int lrow = lane & 15;
    const int lgrp = lane >> 4;
    const int n = nq * 64 + wave * 16 + lrow;

    f32x4_t acc = (f32x4_t){0.f, 0.f, 0.f, 0.f};
    const float* wcol = w1 + n;        // w1[k][n], stride DH_
    #pragma unroll
    for (int s = 0; s < 16; ++s) {
        bf16x8_t a = *(const bf16x8_t*)&Rs[lrow][s * 32 + lgrp * 8];
        const float* wp = wcol + (size_t)(s * 32 + lgrp * 8) * DH_;
        bf16x8_t bfr;
        #pragma unroll
        for (int j = 0; j < 8; ++j) bfr[j] = to_bf16(wp[(size_t)j * DH_]);
        acc = __builtin_amdgcn_mfma_f32_16x16x32_bf16(a, bfr, acc, 0, 0, 0);
    }
    const float b1v = b1[n];
    const float w2v = w2[n];
    float rowpart[4];
    #pragma unroll
    for (int r = 0; r < 4; ++r) {
        float h = acc[r] + b1v;
        h = h > 0.f ? h : 0.f;
        rowpart[r] = h * w2v;
    }
    #pragma unroll
    for (int r = 0; r < 4; ++r) {
        float v = rowpart[r];
        v += __shfl_xor(v, 1);
        v += __shfl_xor(v, 2);
        v += __shfl_xor(v, 4);
        v += __shfl_xor(v, 8);
        if (lrow == 0) part[wave][lgrp * 4 + r] = v;
    }
    __syncthreads();
    if (t < 16)
        fused4[nq * (B_ * L_) + m0 + t] =
            part[0][t] + part[1][t] + part[2][t] + part[3][t];
}

// ---------------- flash attention: reg-staged f32 K/V, conflict-free LDS -----
// R1 pipeline (no K/V pre-conversion: global f32 -> regs -> bf16 LDS, double-
// buffered, one barrier/step) with R4's conflict-free geometry: 128B rows +
// low-3-bit XOR slot swizzle. Write-side mappings are bank-uniform:
//   K: 16 lanes/row cover all 32 banks (8B writes at 16 distinct half-slots)
//   V: b128 writes, 8 lanes per 4-bank group = full LDS bandwidth
// Momentum computed from the 4 mlp partials (8 L3-hot loads per entry).
__global__ __launch_bounds__(256) void attn_kernel(
        const float* __restrict__ Q, const float* __restrict__ K,
        const float* __restrict__ V, const float* __restrict__ fused4,
        const float* __restrict__ alpha_trend, float* __restrict__ out) {
    __shared__ __align__(16) bf16_t Ks[2][64][64];   // [buf][perm row][e swz]
    __shared__ __align__(16) bf16_t Vt[2][64][64];   // [buf][d][s swz]
    __shared__ float moms[2][64];

    const int bid = blockIdx.x;
    const int bh  = bid & 31;
    const int grp = bid >> 5;
    // balanced pairing: consecutive bids alternate heavy/light (sum 33 steps)
    const int qt  = (grp & 1) ? (grp >> 1) : 31 - (grp >> 1);
    const int h = bh & 15, b = bh >> 4;
    const int q0 = qt << 6;
    const int tid = threadIdx.x;
    const int wave = tid >> 6, lane = tid & 63;
    const int lrow = lane & 15, lgrp = lane >> 4;

    const float c1 = 0.18033688f;      // 0.125 * log2(e)
    const float ascale2 = alpha_trend[h] * c1;
    const size_t bl = (size_t)b * L_;
    const int qw0 = q0 + wave * 16;

    const float* Kb = K + (bl * H_ + h) * E_;
    const float* Vb = V + (bl * H_ + h) * D_;
    const float* f4 = fused4 + bl;     // + nq*4096 per partial

    auto fsum = [&](int i) {
        return f4[i] + f4[4096 + i] + f4[8192 + i] + f4[12288 + i];
    };

    // Q fragments, prescaled by c1 (RNE, once)
    bf16x8_t a_lo, a_hi;
    {
        const float* qp = Q + ((bl + qw0 + lrow) * H_ + h) * E_ + lgrp * 8;
        f32x4_t v0 = *(const f32x4_t*)(qp);
        f32x4_t v1 = *(const f32x4_t*)(qp + 4);
        f32x4_t v2 = *(const f32x4_t*)(qp + 32);
        f32x4_t v3 = *(const f32x4_t*)(qp + 36);
        #pragma unroll
        for (int k = 0; k < 4; ++k) {
            a_lo[k]     = to_bf16(v0[k] * c1);
            a_lo[4 + k] = to_bf16(v1[k] * c1);
            a_hi[k]     = to_bf16(v2[k] * c1);
            a_hi[4 + k] = to_bf16(v3[k] * c1);
        }
    }
    const int qg = qw0 + lrow;
    const float mq = (qg > 0) ? fsum(qg) - fsum(qg - 1) : 0.f;

    // staging thread mapping
    const int krow = tid >> 4;              // K source row (mod 16)
    const int ke0  = (tid & 15) << 2;       // 4-element group
    // permuted dest row for s = krow + 16u: p0 + (u&1)*8 + (u>>1)*32
    const int p0   = (krow & 3) | (((krow >> 3) & 1) << 2) | (((krow >> 2) & 1) << 4);
    const int kslot = ke0 >> 3;             // 16B slot of this 4-element group
    const int khalf = (ke0 & 4) << 1;       // byte offset within slot (0 or 8)
    const int vd   = tid & 63;
    const int vsb  = tid >> 6;
    const int vswz = vd & 7;                // low row bits -> bank spread

    f32x4_t Oacc[4];
    #pragma unroll
    for (int c = 0; c < 4; ++c) Oacc[c] = (f32x4_t){0.f, 0.f, 0.f, 0.f};
    float rowsum = 0.f;

    // prologue: preload tile 0 into registers
    TileRegs tr;
    {
        #pragma unroll
        for (int u = 0; u < 4; ++u)
            tr.k[u] = *(const f32x4_t*)&Kb[(krow + u * 16) * (H_ * E_) + ke0];
        #pragma unroll
        for (int j = 0; j < 16; ++j)
            tr.v[j] = Vb[(vsb * 16 + j) * (H_ * D_) + vd];
        tr.m = (tid > 0 && tid < 64) ? fsum(tid) - fsum(tid - 1) : 0.f;
    }

    const int bb = lrow & 7;                // read-side swizzle (row&7)

    for (int st = 0; st <= qt; ++st) {
        const int buf = st & 1;
        char* ksb = (char*)&Ks[buf][0][0];
        char* vtb = (char*)&Vt[buf][0][0];

        // registers -> LDS (bf16, permuted rows + slot swizzle)
        #pragma unroll
        for (int u = 0; u < 4; ++u) {
            uint2 p;
            p.x = bpack(tr.k[u][1], tr.k[u][0]);
            p.y = bpack(tr.k[u][3], tr.k[u][2]);
            const int pr = p0 + (u & 1) * 8 + (u >> 1) * 32;
            const int boff = (((kslot ^ (pr & 7)) << 4) | khalf);
            *(uint2*)(ksb + pr * 128 + boff) = p;
        }
        #pragma unroll
        for (int gg = 0; gg < 2; ++gg) {    // V: 2x 16B (8 s-values each)
            uint4 q;
            q.x = bpack(tr.v[gg * 8 + 1], tr.v[gg * 8 + 0]);
            q.y = bpack(tr.v[gg * 8 + 3], tr.v[gg * 8 + 2]);
            q.z = bpack(tr.v[gg * 8 + 5], tr.v[gg * 8 + 4]);
            q.w = bpack(tr.v[gg * 8 + 7], tr.v[gg * 8 + 6]);
            const int boff = ((vsb * 2 + gg) ^ vswz) << 4;
            *(uint4*)(vtb + vd * 128 + boff) = q;
        }
        if (tid < 64) moms[buf][tid] = tr.m;
        __syncthreads();   // single barrier per step (double-buffered LDS)

        // issue next tile's global loads (latency hidden behind compute)
        if (st < qt) {
            const int s0n = (st + 1) << 6;
            #pragma unroll
            for (int u = 0; u < 4; ++u)
                tr.k[u] = *(const f32x4_t*)&Kb[(s0n + krow + u * 16) * (H_ * E_) + ke0];
            #pragma unroll
            for (int j = 0; j < 16; ++j)
                tr.v[j] = Vb[(s0n + vsb * 16 + j) * (H_ * D_) + vd];
            tr.m = (tid < 64) ? fsum(s0n + tid) - fsum(s0n + tid - 1) : 0.f;
        }

        // S^T = K Q^T (swapped operands; log2 domain via Q prescale)
        // lane holds S[q=qw0+lrow][s = 8*lgrp + 4*(c&1) + r + 32*(c>>1)]
        f32x4_t Sacc[4];
        #pragma unroll
        for (int c = 0; c < 4; ++c) Sacc[c] = (f32x4_t){0.f, 0.f, 0.f, 0.f};
        __builtin_amdgcn_s_setprio(1);
        #pragma unroll
        for (int c = 0; c < 4; ++c) {
            const char* kr = ksb + (c * 16 + lrow) * 128;
            bf16x8_t k_lo = *(const bf16x8_t*)(kr + ((lgrp ^ bb) << 4));
            bf16x8_t k_hi = *(const bf16x8_t*)(kr + (((4 + lgrp) ^ bb) << 4));
            Sacc[c] = __builtin_amdgcn_mfma_f32_16x16x32_bf16(k_lo, a_lo, Sacc[c], 0, 0, 0);
            Sacc[c] = __builtin_amdgcn_mfma_f32_16x16x32_bf16(k_hi, a_hi, Sacc[c], 0, 0, 0);
        }
        __builtin_amdgcn_s_setprio(0);

        // P = exp2(S - ascale2*|dm|)
        float rowe[4][4];
        #pragma unroll
        for (int c = 0; c < 4; ++c) {
            const int sb = lgrp * 8 + ((c & 1) << 2) + ((c >> 1) << 5);
            f32x4_t ms4 = *(const f32x4_t*)&moms[buf][sb];
            #pragma unroll
            for (int r = 0; r < 4; ++r) {
                float arg = Sacc[c][r] - ascale2 * fabsf(mq - ms4[r]);
                rowe[c][r] = __builtin_amdgcn_exp2f(arg);
            }
        }
        if (st == qt) {                // causal mask on diagonal tile
            const int s0 = st << 6;
            #pragma unroll
            for (int c = 0; c < 4; ++c) {
                const int sg0 = s0 + lgrp * 8 + ((c & 1) << 2) + ((c >> 1) << 5);
                #pragma unroll
                for (int r = 0; r < 4; ++r)
                    if (sg0 + r > qg) rowe[c][r] = 0.f;
            }
        }
        #pragma unroll
        for (int c = 0; c < 4; ++c)
            rowsum += (rowe[c][0] + rowe[c][1]) + (rowe[c][2] + rowe[c][3]);

        // O += P V : P fragments lane-local, pack to bf16
        #pragma unroll
        for (int hh = 0; hh < 2; ++hh) {
            union { unsigned u[4]; bf16x8_t v; } pa;
            pa.u[0] = bpack(rowe[2 * hh][1],     rowe[2 * hh][0]);
            pa.u[1] = bpack(rowe[2 * hh][3],     rowe[2 * hh][2]);
            pa.u[2] = bpack(rowe[2 * hh + 1][1], rowe[2 * hh + 1][0]);
            pa.u[3] = bpack(rowe[2 * hh + 1][3], rowe[2 * hh + 1][2]);
            __builtin_amdgcn_s_setprio(1);
            #pragma unroll
            for (int c2 = 0; c2 < 4; ++c2) {
                const int row = c2 * 16 + lrow;
                bf16x8_t bv = *(const bf16x8_t*)(vtb + row * 128 +
                                                 (((hh * 4 + lgrp) ^ bb) << 4));
                Oacc[c2] = __builtin_amdgcn_mfma_f32_16x16x32_bf16(pa.v, bv, Oacc[c2], 0, 0, 0);
            }
            __builtin_amdgcn_s_setprio(0);
        }
    }

    // epilogue: full row sums via 2 shuffles, normalize, store
    float rs = rowsum;
    rs += __shfl_xor(rs, 16);
    rs += __shfl_xor(rs, 32);
    #pragma unroll
    for (int r = 0; r < 4; ++r) {
        float inv = 1.f / __shfl(rs, lgrp * 4 + r);
        size_t orow = ((bl + qw0 + lgrp * 4 + r) * H_ + h) * D_;
        #pragma unroll
        for (int c = 0; c < 4; ++c)
            out[orow + c * 16 + lrow] = Oacc[c][r] * inv;
    }
}

extern "C" void kernel_launch(void* const* d_in, const int* in_sizes, int n_in,
                              void* d_out, int out_size, void* d_ws, size_t ws_size,
                              hipStream_t stream) {
    const float* Q     = (const float*)d_in[0];
    const float* K     = (const float*)d_in[1];
    const float* V     = (const float*)d_in[2];
    const float* raw   = (const float*)d_in[3];
    const float* w1    = (const float*)d_in[4];
    const float* b1    = (const float*)d_in[5];
    const float* w2    = (const float*)d_in[6];
    const float* alpha = (const float*)d_in[8];
    float* out = (float*)d_out;

    float* fused4 = (float*)d_ws;      // 4 x 4096 f32 partials (unique-writer)

    mlp_kernel<<<B_ * L_ / 16 * 4, 256, 0, stream>>>(raw, w1, b1, w2, fused4);
    attn_kernel<<<B_ * H_ * (L_ / 64), 256, 0, stream>>>(Q, K, V, fused4, alpha, out);
}